// Round 6
// baseline (2945.977 us; speedup 1.0000x reference)
//
#include <hip/hip_runtime.h>

#define NN 50000
#define NE 800000
#define DD 256
#define NG 64
#define MPAD 50048  // 128 * 391

// counting-sort parameters
#define HC 64          // edge chunks (NE/HC = 12500 < 65536, u16-safe)
#define EPC (NE / HC)  // 12500
#define HBINS 32768    // bins/part, u16-packed -> 64 KB LDS (2 parts)
#define FBINS 16384    // bins/part, u32 counters -> 64 KB LDS (4 parts)

// parallel scan
#define SB 196         // SB*256 = 50176 >= NN+1

// tiled-scatter aggregation
#define TN 128                    // dst nodes per tile (128-aligned -> rel = dst & 127)
#define NT ((NN + TN - 1) / TN)   // 391
#define ECH 1024                  // edges staged per chunk

// pool split-K GEMM
#define B2 384
#define KCH 131        // ceil(NN/B2)

typedef __attribute__((ext_vector_type(8))) short bf16x8;
typedef __attribute__((ext_vector_type(4))) float f32x4;

__device__ __forceinline__ float bf2f(unsigned short u) {
  union { unsigned int i; float f; } v; v.i = ((unsigned int)u) << 16; return v.f;
}
__device__ __forceinline__ unsigned short f2bf(float f) {
  union { float f; unsigned int i; } v; v.f = f;
  unsigned int x = v.i;
  x += 0x7fffu + ((x >> 16) & 1u);  // RNE
  return (unsigned short)(x >> 16);
}

// ---------------- init / casts ----------------
__global__ void k_zero(unsigned int* __restrict__ p, int n) {
  int i = blockIdx.x * blockDim.x + threadIdx.x;
  int st = gridDim.x * blockDim.x;
  for (; i < n; i += st) p[i] = 0u;
}

__global__ void k_castW(const float* __restrict__ W, unsigned short* __restrict__ Wt) {
  int i = blockIdx.x * blockDim.x + threadIdx.x;
  int n = i >> 8, k = i & 255;
  Wt[i] = f2bf(W[k * 256 + n]);
}

__global__ void k_castX(const float* __restrict__ x, unsigned short* __restrict__ xb) {
  int i = blockIdx.x * blockDim.x + threadIdx.x;
  int e = i * 4;
  int row = e >> 8;
  float4 v = make_float4(0.f, 0.f, 0.f, 0.f);
  if (row < NN) v = *(const float4*)(x + e);
  ushort4 u;
  u.x = f2bf(v.x); u.y = f2bf(v.y); u.z = f2bf(v.z); u.w = f2bf(v.w);
  *(ushort4*)(xb + e) = u;
}

// ---------------- GEMM: h1 (slice-major [8][MPAD][32]) = A[MPAD][256] @ B ----------------
__global__ __launch_bounds__(256) void k_gemm(const unsigned short* __restrict__ A,
                                              const unsigned short* __restrict__ Bt,
                                              unsigned short* __restrict__ C) {
  __shared__ unsigned short As[128][40];
  __shared__ unsigned short Bs[64][40];
  int tid = threadIdx.x;
  int lane = tid & 63;
  int wave = tid >> 6;
  int wm = wave >> 1, wn = wave & 1;
  int m0 = blockIdx.x * 128, n0 = blockIdx.y * 64;
  int l15 = lane & 15, l4 = lane >> 4;
  f32x4 acc[4][2] = {};

  for (int ks = 0; ks < 8; ++ks) {
    int k0 = ks * 32;
    {
      int c = tid, r = c >> 2, cc = c & 3;
      *(uint4*)(&As[r][cc * 8]) = *(const uint4*)(A + (size_t)(m0 + r) * 256 + k0 + cc * 8);
      c = tid + 256; r = c >> 2; cc = c & 3;
      *(uint4*)(&As[r][cc * 8]) = *(const uint4*)(A + (size_t)(m0 + r) * 256 + k0 + cc * 8);
      c = tid; r = c >> 2; cc = c & 3;
      *(uint4*)(&Bs[r][cc * 8]) = *(const uint4*)(Bt + (size_t)(n0 + r) * 256 + k0 + cc * 8);
    }
    __syncthreads();
    bf16x8 a[4], b[2];
#pragma unroll
    for (int fm = 0; fm < 4; ++fm)
      a[fm] = *(const bf16x8*)(&As[wm * 64 + fm * 16 + l15][l4 * 8]);
#pragma unroll
    for (int fn = 0; fn < 2; ++fn)
      b[fn] = *(const bf16x8*)(&Bs[wn * 32 + fn * 16 + l15][l4 * 8]);
#pragma unroll
    for (int fm = 0; fm < 4; ++fm)
#pragma unroll
      for (int fn = 0; fn < 2; ++fn)
        acc[fm][fn] = __builtin_amdgcn_mfma_f32_16x16x32_bf16(a[fm], b[fn], acc[fm][fn], 0, 0, 0);
    __syncthreads();
  }
  int r0 = l4 * 4;
#pragma unroll
  for (int fm = 0; fm < 4; ++fm)
#pragma unroll
    for (int fn = 0; fn < 2; ++fn) {
      int row = m0 + wm * 64 + fm * 16 + r0;
      int col = n0 + wn * 32 + fn * 16 + l15;
      size_t sbase = (size_t)(col >> 5) * MPAD * 32 + (size_t)(col & 31);
#pragma unroll
      for (int r = 0; r < 4; ++r)
        C[sbase + (size_t)(row + r) * 32] = f2bf(acc[fm][fn][r]);
    }
}

// ---------------- counting sort (shared for dst-sort and src-sort) ----------------
__global__ __launch_bounds__(256) void k_hist2(const int* __restrict__ key,
                                               unsigned int* __restrict__ partial) {
  __shared__ unsigned int lh[HBINS / 2];  // 64 KB u16-packed
  int tid = threadIdx.x;
  int c = blockIdx.x, p = blockIdx.y;
  for (int w = tid; w < HBINS / 2; w += 256) lh[w] = 0u;
  __syncthreads();
  int lo = c * EPC, hi = lo + EPC;
  int b0 = p * HBINS;
  for (int i = lo + tid; i < hi; i += 256) {
    int rel = key[i] - b0;
    if ((unsigned)rel < (unsigned)HBINS)
      atomicAdd(&lh[rel >> 1], 1u << ((rel & 1) * 16));
  }
  __syncthreads();
  int wbase = p * (HBINS / 2);
  for (int w = tid; w < HBINS / 2; w += 256) {
    int gw = wbase + w;
    if (gw < NN / 2) partial[(size_t)c * (NN / 2) + gw] = lh[w];
  }
}

__global__ void k_reduce(const unsigned int* __restrict__ partial, int* __restrict__ deg) {
  int w = blockIdx.x * blockDim.x + threadIdx.x;
  if (w >= NN / 2) return;
  unsigned int sl = 0, sh = 0;
#pragma unroll
  for (int c = 0; c < HC; ++c) {
    unsigned int v = partial[(size_t)c * (NN / 2) + w];
    sl += v & 0xffffu;
    sh += v >> 16;
  }
  *(int2*)(deg + 2 * w) = make_int2((int)sl, (int)sh);
}

__global__ void k_dinv(const int* __restrict__ deg, float* __restrict__ dinv) {
  int i = blockIdx.x * blockDim.x + threadIdx.x;
  if (i < NN) dinv[i] = rsqrtf((float)deg[i] + 1.0f);  // +1 self-loop
}

// 3-dispatch parallel exclusive scan: deg[NN] -> rp[NN+1]
__global__ __launch_bounds__(256) void k_bsum(const int* __restrict__ deg, int* __restrict__ bsums) {
  __shared__ int s[256];
  int b = blockIdx.x, t = threadIdx.x, i = b * 256 + t;
  int v = (i < NN) ? deg[i] : 0;
  s[t] = v; __syncthreads();
  for (int off = 128; off > 0; off >>= 1) {
    if (t < off) s[t] += s[t + off];
    __syncthreads();
  }
  if (t == 0) bsums[b] = s[0];
}
__global__ __launch_bounds__(256) void k_sscan(int* __restrict__ bsums) {
  __shared__ int s[256];
  int t = threadIdx.x;
  int v = (t < SB) ? bsums[t] : 0;
  s[t] = v; __syncthreads();
  for (int off = 1; off < 256; off <<= 1) {
    int tmp = (t >= off) ? s[t - off] : 0;
    __syncthreads();
    s[t] += tmp;
    __syncthreads();
  }
  if (t < SB) bsums[t] = s[t] - v;  // exclusive
}
__global__ __launch_bounds__(256) void k_fillrp(const int* __restrict__ deg,
                                                const int* __restrict__ bsums,
                                                int* __restrict__ rp) {
  __shared__ int s[256];
  int b = blockIdx.x, t = threadIdx.x, i = b * 256 + t;
  int v = (i < NN) ? deg[i] : 0;
  s[t] = v; __syncthreads();
  for (int off = 1; off < 256; off <<= 1) {
    int tmp = (t >= off) ? s[t - off] : 0;
    __syncthreads();
    s[t] += tmp;
    __syncthreads();
  }
  int excl = bsums[b] + s[t] - v;
  if (i <= NN) rp[i] = excl;
}

// base[c][b] = rp[b] + sum_{c'<c} partial16[c'][b]
__global__ void k_base(const unsigned short* __restrict__ partial16,
                       const int* __restrict__ rp, int* __restrict__ base) {
  int b = blockIdx.x * blockDim.x + threadIdx.x;
  if (b >= NN) return;
  int run = rp[b];
#pragma unroll
  for (int c = 0; c < HC; ++c) {
    base[(size_t)c * NN + b] = run;
    run += (int)partial16[(size_t)c * NN + b];
  }
}

// graph boundaries from sorted batch
__global__ void k_bounds(const int* __restrict__ batch, int* __restrict__ starts) {
  int i = blockIdx.x * blockDim.x + threadIdx.x;
  if (i > NN) return;
  if (i == 0) {
    int b0 = batch[0];
    for (int g = 0; g <= b0; ++g) starts[g] = 0;
  } else if (i == NN) {
    int bl = batch[NN - 1];
    for (int g = bl + 1; g <= NG; ++g) starts[g] = NN;
  } else {
    int a = batch[i - 1], b = batch[i];
    for (int g = a + 1; g <= b; ++g) starts[g] = i;
  }
}

// in-CSR fill (keyed by dst): csr_pk = ((dst&127)<<16)|src, csr_norm
__global__ __launch_bounds__(256) void k_fill2(const int* __restrict__ src,
                                               const int* __restrict__ dst,
                                               const int* __restrict__ base,
                                               const float* __restrict__ dinv,
                                               unsigned int* __restrict__ csr_pk,
                                               float* __restrict__ csr_norm) {
  __shared__ unsigned int pos[FBINS];  // 64 KB
  int tid = threadIdx.x;
  int c = blockIdx.x, p = blockIdx.y;
  int b0 = p * FBINS;
  for (int w = tid; w < FBINS; w += 256) {
    int gb = b0 + w;
    pos[w] = (gb < NN) ? (unsigned int)base[(size_t)c * NN + gb] : 0u;
  }
  __syncthreads();
  int lo = c * EPC, hi = lo + EPC;
  for (int i = lo + tid; i < hi; i += 256) {
    int d = dst[i];
    int s = src[i];
    int rel = d - b0;
    if ((unsigned)rel < (unsigned)FBINS) {
      int idx = (int)atomicAdd(&pos[rel], 1u);
      csr_pk[idx] = ((unsigned int)(d & (TN - 1)) << 16) | (unsigned int)s;
      csr_norm[idx] = dinv[s] * dinv[d];
    }
  }
}

// out-CSR fill (keyed by src): csr2 = pack(coef, graph(dst))
__global__ __launch_bounds__(256) void k_fill3(const int* __restrict__ src,
                                               const int* __restrict__ dst,
                                               const int* __restrict__ base,
                                               const float* __restrict__ dinv,
                                               const int* __restrict__ batch,
                                               unsigned int* __restrict__ csr2) {
  __shared__ unsigned int pos[FBINS];
  int tid = threadIdx.x;
  int c = blockIdx.x, p = blockIdx.y;
  int b0 = p * FBINS;
  for (int w = tid; w < FBINS; w += 256) {
    int gb = b0 + w;
    pos[w] = (gb < NN) ? (unsigned int)base[(size_t)c * NN + gb] : 0u;
  }
  __syncthreads();
  int lo = c * EPC, hi = lo + EPC;
  for (int i = lo + tid; i < hi; i += 256) {
    int s = src[i];
    int d = dst[i];
    int rel = s - b0;
    if ((unsigned)rel < (unsigned)FBINS) {
      int idx = (int)atomicAdd(&pos[rel], 1u);
      float coef = dinv[s] * dinv[d];
      union { float f; unsigned int u; } cv; cv.f = coef;
      csr2[idx] = (cv.u & 0xFFFFFFC0u) | (unsigned int)batch[d];
    }
  }
}

// ---------------- tiled-scatter aggregation: z = elu(A_norm @ h1 + b1) ----------------
// grid (8 slices, NT tiles): linear id % 8 = slice -> XCD L2 affinity (h1 slice 3.2 MB
// L2-resident). Block: flat edge stream, 8 groups x 32 lanes, LDS f32 scatter (bank-
// conflict-free: bank = f), no per-node barriers, iterations independent -> deep pipeline.
__global__ __launch_bounds__(256) void k_agg1t(const unsigned short* __restrict__ h1,
                                               const unsigned int* __restrict__ csr_pk,
                                               const float* __restrict__ csr_nrm,
                                               const int* __restrict__ rp,
                                               const float* __restrict__ dinv,
                                               const float* __restrict__ b1,
                                               unsigned short* __restrict__ z) {
  __shared__ float acc[TN * 32];     // 16 KB
  __shared__ unsigned int spk[ECH];  // 4 KB
  __shared__ float snm[ECH];         // 4 KB
  int s = blockIdx.x, tb = blockIdx.y;
  int tid = threadIdx.x, f = tid & 31, eg = tid >> 5;
  const unsigned short* h1s = h1 + (size_t)s * MPAD * 32;
  int lo = tb * TN, hi = min(lo + TN, NN);
  int e0 = rp[lo], e1 = rp[hi];
  for (int w = tid; w < TN * 32; w += 256) acc[w] = 0.f;
  float bias = b1[s * 32 + f];
  __syncthreads();
  for (int cs = e0; cs < e1; cs += ECH) {
    int cn = min(ECH, e1 - cs);
    for (int w = tid; w < cn; w += 256) {
      spk[w] = __builtin_nontemporal_load(&csr_pk[cs + w]);
      snm[w] = __builtin_nontemporal_load(&csr_nrm[cs + w]);
    }
    __syncthreads();
    int per = (cn + 7) >> 3;
    int gs = eg * per, ge = min(gs + per, cn);
#pragma unroll 4
    for (int e = gs; e < ge; ++e) {
      unsigned int pk = spk[e];
      float nm = snm[e];
      int srcn = (int)(pk & 0xFFFFu);
      int rel = (int)(pk >> 16);
      float v = nm * bf2f(h1s[(size_t)srcn * 32 + f]);
      atomicAdd(&acc[rel * 32 + f], v);
    }
    __syncthreads();
  }
  // epilogue: self-loop + bias + ELU + write
  for (int i = eg; i < hi - lo; i += 8) {
    int v = lo + i;
    float di = dinv[v];
    float t = acc[i * 32 + f] + di * di * bf2f(h1s[(size_t)v * 32 + f]) + bias;
    float ez = t > 0.f ? t : expm1f(t);
    z[(size_t)v * 256 + s * 32 + f] = f2bf(ez);
  }
}

// ---------------- build dense P [NN][64] f32 (row v owned by one thread) ----------------
__global__ void k_fillP(const unsigned int* __restrict__ csr2,
                        const int* __restrict__ rp2,
                        const float* __restrict__ dinv,
                        const int* __restrict__ batch,
                        float* __restrict__ P) {
  int v = blockIdx.x * blockDim.x + threadIdx.x;
  if (v >= NN) return;
  float* row = P + (size_t)v * 64;
  int e0 = rp2[v], e1 = rp2[v + 1];
  for (int e = e0; e < e1; ++e) {
    unsigned int u = csr2[e];
    union { unsigned int ui; float f; } cv; cv.ui = u & 0xFFFFFFC0u;
    row[u & 63u] += cv.f;
  }
  float di = dinv[v];
  row[batch[v]] += di * di;
}

// ---------------- pool split-K GEMM: part[kb] = P[chunk]^T @ z[chunk] ----------------
__global__ __launch_bounds__(256) void k_poolg(const unsigned short* __restrict__ z,
                                               const float* __restrict__ P,
                                               float* __restrict__ part) {
  __shared__ float Pl[KCH * 64];  // 33.5 KB
  int kb = blockIdx.x, tid = threadIdx.x;
  int k0 = kb * KCH;
  int n = min(KCH, NN - k0);
  int n4 = n * 16;
  const float4* Pg = (const float4*)(P + (size_t)k0 * 64);
  for (int w = tid; w < n4; w += 256) ((float4*)Pl)[w] = Pg[w];
  __syncthreads();
  float acc[64];
#pragma unroll
  for (int g = 0; g < 64; ++g) acc[g] = 0.f;
  for (int k = 0; k < n; ++k) {
    float zv = bf2f(z[(size_t)(k0 + k) * 256 + tid]);
    const float4* pr = (const float4*)&Pl[k * 64];
#pragma unroll
    for (int q = 0; q < 16; ++q) {
      float4 p = pr[q];
      acc[q * 4 + 0] += p.x * zv;
      acc[q * 4 + 1] += p.y * zv;
      acc[q * 4 + 2] += p.z * zv;
      acc[q * 4 + 3] += p.w * zv;
    }
  }
  float* dst = part + (size_t)kb * 64 * 256 + tid;
#pragma unroll
  for (int g = 0; g < 64; ++g) dst[g * 256] = acc[g];
}

__global__ __launch_bounds__(256) void k_preduce(const float* __restrict__ part,
                                                 float* __restrict__ pool) {
  int g = blockIdx.x, j = threadIdx.x;
  float s = 0.f;
  for (int b = 0; b < B2; ++b) s += part[((size_t)b * 64 + g) * 256 + j];
  pool[g * 256 + j] = s;
}

// ---------------- f = (pool/c) @ W2 + b2 ----------------
__global__ __launch_bounds__(256) void k_featF(const float* __restrict__ pool_s,
                                               const float* __restrict__ pool_n,
                                               const int* __restrict__ st_s,
                                               const int* __restrict__ st_n,
                                               const float* __restrict__ W2,
                                               const float* __restrict__ b2,
                                               float* __restrict__ fstate,
                                               float* __restrict__ fnext,
                                               float* __restrict__ out) {
  int g = blockIdx.x, which = blockIdx.y, j = threadIdx.x;
  const float* pool = which ? pool_n : pool_s;
  const int* st = which ? st_n : st_s;
  int c = st[g + 1] - st[g];
  __shared__ float v[256];
  float cc = fmaxf((float)c, 1.0f);
  v[j] = pool[g * 256 + j] / cc;
  __syncthreads();
  float acc = 0.f;
  for (int k = 0; k < 256; ++k) acc += v[k] * W2[k * 256 + j];
  float val = (c > 0) ? (acc + b2[j]) : 0.f;
  if (which) { fnext[g * 256 + j] = val; out[g * 256 + j] = val; }
  else fstate[g * 256 + j] = val;
}

// ---------------- heads ----------------
__global__ __launch_bounds__(256) void k_head(const float* __restrict__ fstate,
                                              const float* __restrict__ fnext,
                                              const int* __restrict__ action,
                                              const float* __restrict__ Wf, const float* __restrict__ bfv,
                                              const float* __restrict__ Wi1, const float* __restrict__ bi1,
                                              const float* __restrict__ Wi2, const float* __restrict__ bi2,
                                              const float* __restrict__ Wi3, const float* __restrict__ bi3,
                                              float* __restrict__ out) {
  int g = blockIdx.x, j = threadIdx.x;
  __shared__ float fs[256], fn_[256], z1[128], z2[128];
  fs[j] = fstate[g * 256 + j];
  fn_[j] = fnext[g * 256 + j];
  __syncthreads();
  int a = action[g];
  float acc = bfv[j] + Wf[a * 256 + j];
  for (int k = 0; k < 256; ++k) acc += fs[k] * Wf[(16 + k) * 256 + j];
  out[16384 + g * 256 + j] = acc;
  if (j < 128) {
    float t = bi1[j];
    for (int k = 0; k < 256; ++k)
      t += fs[k] * Wi1[k * 128 + j] + fn_[k] * Wi1[(256 + k) * 128 + j];
    z1[j] = fmaxf(t, 0.f);
  }
  __syncthreads();
  if (j < 128) {
    float t = bi2[j];
    for (int k = 0; k < 128; ++k) t += z1[k] * Wi2[k * 128 + j];
    z2[j] = fmaxf(t, 0.f);
  }
  __syncthreads();
  if (j < 16) {
    float t = bi3[j];
    for (int k = 0; k < 128; ++k) t += z2[k] * Wi3[k * 16 + j];
    out[32768 + g * 16 + j] = t;
  }
}

// ---------------- workspace layout ----------------
static constexpr size_t AL(size_t x) { return (x + 255) & ~(size_t)255; }
static constexpr size_t O_XB   = 0;                                    // 25.6 MB (part aliases)
static constexpr size_t O_H1   = O_XB + AL((size_t)MPAD * DD * 2);     // 25.6 MB (sort scratch + P alias)
static constexpr size_t O_Z    = O_H1 + AL((size_t)MPAD * DD * 2);     // 25.6 MB
static constexpr size_t O_CSRS = O_Z + AL((size_t)NN * DD * 2);
static constexpr size_t O_CSRN = O_CSRS + AL((size_t)NE * 4);
static constexpr size_t O_CSR2 = O_CSRN + AL((size_t)NE * 4);
static constexpr size_t O_RP   = O_CSR2 + AL((size_t)NE * 4);
static constexpr size_t O_RP2  = O_RP + AL((size_t)(NN + 1) * 4);
static constexpr size_t O_DINV = O_RP2 + AL((size_t)(NN + 1) * 4);
static constexpr size_t O_DEG  = O_DINV + AL((size_t)NN * 4);
static constexpr size_t O_BS   = O_DEG + AL((size_t)NN * 4);
static constexpr size_t O_ST0  = O_BS + AL(256 * 4);
static constexpr size_t O_ST1  = O_ST0 + AL((NG + 1) * 4);
static constexpr size_t O_WT   = O_ST1 + AL((NG + 1) * 4);
static constexpr size_t O_PS   = O_WT + AL((size_t)DD * DD * 2);
static constexpr size_t O_PN   = O_PS + AL((size_t)NG * DD * 4);
static constexpr size_t O_FS   = O_PN + AL((size_t)NG * DD * 4);
static constexpr size_t O_FN   = O_FS + AL((size_t)NG * DD * 4);
static constexpr size_t O_END  = O_FN + AL((size_t)NG * DD * 4);
// aliased scratch:
static constexpr size_t O_PART = O_H1;                                  // HC*NN/2 u32 = 6.4 MB
static constexpr size_t O_BASE = O_H1 + AL((size_t)HC * (NN / 2) * 4);  // HC*NN u32 = 12.8 MB
static constexpr size_t O_P    = O_H1;                                  // NN*64 f32 = 12.8 MB (after agg1t)
static constexpr size_t O_PB   = O_XB;                                  // B2*64*256*4 = 25.2 MB

extern "C" void kernel_launch(void* const* d_in, const int* in_sizes, int n_in,
                              void* d_out, int out_size, void* d_ws, size_t ws_size,
                              hipStream_t stream) {
  const float* x_s     = (const float*)d_in[0];
  const int*   ei_s    = (const int*)d_in[1];
  const int*   batch_s = (const int*)d_in[2];
  const float* x_n     = (const float*)d_in[3];
  const int*   ei_n    = (const int*)d_in[4];
  const int*   batch_n = (const int*)d_in[5];
  const int*   action  = (const int*)d_in[6];
  const float* W1      = (const float*)d_in[7];
  const float* b1      = (const float*)d_in[8];
  const float* W2      = (const float*)d_in[9];
  const float* b2      = (const float*)d_in[10];
  const float* Wf      = (const float*)d_in[11];
  const float* bfv     = (const float*)d_in[12];
  const float* Wi1     = (const float*)d_in[13];
  const float* bi1     = (const float*)d_in[14];
  const float* Wi2     = (const float*)d_in[15];
  const float* bi2     = (const float*)d_in[16];
  const float* Wi3     = (const float*)d_in[17];
  const float* bi3     = (const float*)d_in[18];
  float* out = (float*)d_out;
  char* ws = (char*)d_ws;
  if (ws_size < O_END) return;

  unsigned short* xb  = (unsigned short*)(ws + O_XB);
  unsigned short* h1  = (unsigned short*)(ws + O_H1);
  unsigned short* zb  = (unsigned short*)(ws + O_Z);
  unsigned int* csr_pk = (unsigned int*)(ws + O_CSRS);
  float* csr_nrm = (float*)(ws + O_CSRN);
  unsigned int* csr2 = (unsigned int*)(ws + O_CSR2);
  int*   rp      = (int*)(ws + O_RP);
  int*   rp2     = (int*)(ws + O_RP2);
  float* dinv    = (float*)(ws + O_DINV);
  int*   deg     = (int*)(ws + O_DEG);
  int*   bsums   = (int*)(ws + O_BS);
  unsigned short* Wt = (unsigned short*)(ws + O_WT);
  float* fstate  = (float*)(ws + O_FS);
  float* fnext   = (float*)(ws + O_FN);
  int*   starts[2] = { (int*)(ws + O_ST0), (int*)(ws + O_ST1) };
  float* pool[2]   = { (float*)(ws + O_PS), (float*)(ws + O_PN) };
  unsigned int* partial = (unsigned int*)(ws + O_PART);
  int*          basebuf = (int*)(ws + O_BASE);
  float*        Pmat    = (float*)(ws + O_P);
  float*        part    = (float*)(ws + O_PB);

  k_castW<<<(DD * DD) / 256, 256, 0, stream>>>(W1, Wt);

  const float* xs[2]  = { x_s, x_n };
  const int*   eis[2] = { ei_s, ei_n };
  const int*   bts[2] = { batch_s, batch_n };

  for (int gidx = 0; gidx < 2; ++gidx) {
    const float* x = xs[gidx];
    const int* src = eis[gidx];
    const int* dst = eis[gidx] + NE;
    const int* batch = bts[gidx];

    k_castX<<<(MPAD * DD / 4) / 256, 256, 0, stream>>>(x, xb);

    // --- in-CSR (by dst): deg -> dinv, rp, csr_pk/csr_norm ---
    k_hist2<<<dim3(HC, 2), 256, 0, stream>>>(dst, partial);
    k_reduce<<<(NN / 2 + 255) / 256, 256, 0, stream>>>(partial, deg);
    k_dinv<<<(NN + 255) / 256, 256, 0, stream>>>(deg, dinv);
    k_bsum<<<SB, 256, 0, stream>>>(deg, bsums);
    k_sscan<<<1, 256, 0, stream>>>(bsums);
    k_fillrp<<<SB, 256, 0, stream>>>(deg, bsums, rp);
    k_base<<<(NN + 255) / 256, 256, 0, stream>>>((const unsigned short*)partial, rp, basebuf);
    k_fill2<<<dim3(HC, (NN + FBINS - 1) / FBINS), 256, 0, stream>>>(src, dst, basebuf, dinv,
                                                                    csr_pk, csr_nrm);
    // --- out-CSR (by src): rp2, csr2 ---
    k_hist2<<<dim3(HC, 2), 256, 0, stream>>>(src, partial);
    k_reduce<<<(NN / 2 + 255) / 256, 256, 0, stream>>>(partial, deg);
    k_bsum<<<SB, 256, 0, stream>>>(deg, bsums);
    k_sscan<<<1, 256, 0, stream>>>(bsums);
    k_fillrp<<<SB, 256, 0, stream>>>(deg, bsums, rp2);
    k_base<<<(NN + 255) / 256, 256, 0, stream>>>((const unsigned short*)partial, rp2, basebuf);
    k_fill3<<<dim3(HC, (NN + FBINS - 1) / FBINS), 256, 0, stream>>>(src, dst, basebuf, dinv,
                                                                    batch, csr2);
    k_bounds<<<(NN + 1 + 255) / 256, 256, 0, stream>>>(batch, starts[gidx]);

    // --- dense GEMM (frees sort scratch), tiled-scatter aggregation ---
    k_gemm<<<dim3(MPAD / 128, DD / 64), 256, 0, stream>>>(xb, Wt, h1);
    k_agg1t<<<dim3(8, NT), 256, 0, stream>>>(h1, csr_pk, csr_nrm, rp, dinv, b1, zb);

    // --- pool as dense split-K GEMM (P overwrites h1; part overwrites xb) ---
    k_zero<<<2048, 256, 0, stream>>>((unsigned int*)Pmat, NN * 64);
    k_fillP<<<(NN + 255) / 256, 256, 0, stream>>>(csr2, rp2, dinv, batch, Pmat);
    k_poolg<<<B2, 256, 0, stream>>>(zb, Pmat, part);
    k_preduce<<<NG, 256, 0, stream>>>(part, pool[gidx]);
  }

  k_featF<<<dim3(NG, 2), 256, 0, stream>>>(pool[0], pool[1], starts[0], starts[1], W2, b2,
                                           fstate, fnext, out);
  k_head<<<NG, 256, 0, stream>>>(fstate, fnext, action, Wf, bfv,
                                 Wi1, bi1, Wi2, bi2, Wi3, bi3, out);
}

// Round 7
// 993.424 us; speedup vs baseline: 2.9655x; 2.9655x over previous
//
#include <hip/hip_runtime.h>

#define NN 50000
#define NE 800000
#define DD 256
#define NG 64
#define MPAD 50048  // 128 * 391

// counting-sort parameters
#define HC 64          // edge chunks (NE/HC = 12500)
#define EPC (NE / HC)  // 12500
#define HBINS 32768    // bins/part, u16-packed -> 64 KB LDS (2 parts)
#define FBINS 16384    // bins/part, u32 counters -> 64 KB LDS (4 parts)

// parallel scan
#define SB 196         // SB*256 = 50176 >= NN+1

// tiled aggregation
#define TN 128                    // dst nodes per tile (128-aligned -> rel = dst & 127)
#define NT ((NN + TN - 1) / TN)   // 391

typedef __attribute__((ext_vector_type(8))) short bf16x8;
typedef __attribute__((ext_vector_type(4))) float f32x4;

__device__ __forceinline__ float bf2f(unsigned short u) {
  union { unsigned int i; float f; } v; v.i = ((unsigned int)u) << 16; return v.f;
}
__device__ __forceinline__ unsigned short f2bf(float f) {
  union { float f; unsigned int i; } v; v.f = f;
  unsigned int x = v.i;
  x += 0x7fffu + ((x >> 16) & 1u);  // RNE
  return (unsigned short)(x >> 16);
}

// ---------------- casts ----------------
__global__ void k_castW(const float* __restrict__ W, unsigned short* __restrict__ Wt) {
  int i = blockIdx.x * blockDim.x + threadIdx.x;
  int n = i >> 8, k = i & 255;
  Wt[i] = f2bf(W[k * 256 + n]);
}

__global__ void k_castX(const float* __restrict__ x, unsigned short* __restrict__ xb) {
  int i = blockIdx.x * blockDim.x + threadIdx.x;
  int e = i * 4;
  int row = e >> 8;
  float4 v = make_float4(0.f, 0.f, 0.f, 0.f);
  if (row < NN) v = *(const float4*)(x + e);
  ushort4 u;
  u.x = f2bf(v.x); u.y = f2bf(v.y); u.z = f2bf(v.z); u.w = f2bf(v.w);
  *(ushort4*)(xb + e) = u;
}

// ---------------- GEMM: h1 (slice-major [8][MPAD][32]) = A[MPAD][256] @ B ----------------
__global__ __launch_bounds__(256) void k_gemm(const unsigned short* __restrict__ A,
                                              const unsigned short* __restrict__ Bt,
                                              unsigned short* __restrict__ C) {
  __shared__ unsigned short As[128][40];
  __shared__ unsigned short Bs[64][40];
  int tid = threadIdx.x;
  int lane = tid & 63;
  int wave = tid >> 6;
  int wm = wave >> 1, wn = wave & 1;
  int m0 = blockIdx.x * 128, n0 = blockIdx.y * 64;
  int l15 = lane & 15, l4 = lane >> 4;
  f32x4 acc[4][2] = {};

  for (int ks = 0; ks < 8; ++ks) {
    int k0 = ks * 32;
    {
      int c = tid, r = c >> 2, cc = c & 3;
      *(uint4*)(&As[r][cc * 8]) = *(const uint4*)(A + (size_t)(m0 + r) * 256 + k0 + cc * 8);
      c = tid + 256; r = c >> 2; cc = c & 3;
      *(uint4*)(&As[r][cc * 8]) = *(const uint4*)(A + (size_t)(m0 + r) * 256 + k0 + cc * 8);
      c = tid; r = c >> 2; cc = c & 3;
      *(uint4*)(&Bs[r][cc * 8]) = *(const uint4*)(Bt + (size_t)(n0 + r) * 256 + k0 + cc * 8);
    }
    __syncthreads();
    bf16x8 a[4], b[2];
#pragma unroll
    for (int fm = 0; fm < 4; ++fm)
      a[fm] = *(const bf16x8*)(&As[wm * 64 + fm * 16 + l15][l4 * 8]);
#pragma unroll
    for (int fn = 0; fn < 2; ++fn)
      b[fn] = *(const bf16x8*)(&Bs[wn * 32 + fn * 16 + l15][l4 * 8]);
#pragma unroll
    for (int fm = 0; fm < 4; ++fm)
#pragma unroll
      for (int fn = 0; fn < 2; ++fn)
        acc[fm][fn] = __builtin_amdgcn_mfma_f32_16x16x32_bf16(a[fm], b[fn], acc[fm][fn], 0, 0, 0);
    __syncthreads();
  }
  int r0 = l4 * 4;
#pragma unroll
  for (int fm = 0; fm < 4; ++fm)
#pragma unroll
    for (int fn = 0; fn < 2; ++fn) {
      int row = m0 + wm * 64 + fm * 16 + r0;
      int col = n0 + wn * 32 + fn * 16 + l15;
      size_t sbase = (size_t)(col >> 5) * MPAD * 32 + (size_t)(col & 31);
#pragma unroll
      for (int r = 0; r < 4; ++r)
        C[sbase + (size_t)(row + r) * 32] = f2bf(acc[fm][fn][r]);
    }
}

// ---------------- counting sort (by dst) ----------------
__global__ __launch_bounds__(256) void k_hist2(const int* __restrict__ key,
                                               unsigned int* __restrict__ partial) {
  __shared__ unsigned int lh[HBINS / 2];  // 64 KB u16-packed
  int tid = threadIdx.x;
  int c = blockIdx.x, p = blockIdx.y;
  for (int w = tid; w < HBINS / 2; w += 256) lh[w] = 0u;
  __syncthreads();
  int lo = c * EPC, hi = lo + EPC;
  int b0 = p * HBINS;
  for (int i = lo + tid; i < hi; i += 256) {
    int rel = key[i] - b0;
    if ((unsigned)rel < (unsigned)HBINS)
      atomicAdd(&lh[rel >> 1], 1u << ((rel & 1) * 16));
  }
  __syncthreads();
  int wbase = p * (HBINS / 2);
  for (int w = tid; w < HBINS / 2; w += 256) {
    int gw = wbase + w;
    if (gw < NN / 2) partial[(size_t)c * (NN / 2) + gw] = lh[w];
  }
}

__global__ void k_reduce(const unsigned int* __restrict__ partial, int* __restrict__ deg) {
  int w = blockIdx.x * blockDim.x + threadIdx.x;
  if (w >= NN / 2) return;
  unsigned int sl = 0, sh = 0;
#pragma unroll
  for (int c = 0; c < HC; ++c) {
    unsigned int v = partial[(size_t)c * (NN / 2) + w];
    sl += v & 0xffffu;
    sh += v >> 16;
  }
  *(int2*)(deg + 2 * w) = make_int2((int)sl, (int)sh);
}

__global__ void k_dinv(const int* __restrict__ deg, float* __restrict__ dinv) {
  int i = blockIdx.x * blockDim.x + threadIdx.x;
  if (i < NN) dinv[i] = rsqrtf((float)deg[i] + 1.0f);  // +1 self-loop
}

// 3-dispatch parallel exclusive scan: deg[NN] -> rp[NN+1]
__global__ __launch_bounds__(256) void k_bsum(const int* __restrict__ deg, int* __restrict__ bsums) {
  __shared__ int s[256];
  int b = blockIdx.x, t = threadIdx.x, i = b * 256 + t;
  int v = (i < NN) ? deg[i] : 0;
  s[t] = v; __syncthreads();
  for (int off = 128; off > 0; off >>= 1) {
    if (t < off) s[t] += s[t + off];
    __syncthreads();
  }
  if (t == 0) bsums[b] = s[0];
}
__global__ __launch_bounds__(256) void k_sscan(int* __restrict__ bsums) {
  __shared__ int s[256];
  int t = threadIdx.x;
  int v = (t < SB) ? bsums[t] : 0;
  s[t] = v; __syncthreads();
  for (int off = 1; off < 256; off <<= 1) {
    int tmp = (t >= off) ? s[t - off] : 0;
    __syncthreads();
    s[t] += tmp;
    __syncthreads();
  }
  if (t < SB) bsums[t] = s[t] - v;  // exclusive
}
__global__ __launch_bounds__(256) void k_fillrp(const int* __restrict__ deg,
                                                const int* __restrict__ bsums,
                                                int* __restrict__ rp) {
  __shared__ int s[256];
  int b = blockIdx.x, t = threadIdx.x, i = b * 256 + t;
  int v = (i < NN) ? deg[i] : 0;
  s[t] = v; __syncthreads();
  for (int off = 1; off < 256; off <<= 1) {
    int tmp = (t >= off) ? s[t - off] : 0;
    __syncthreads();
    s[t] += tmp;
    __syncthreads();
  }
  int excl = bsums[b] + s[t] - v;
  if (i <= NN) rp[i] = excl;
}

// base[c][b] = rp[b] + sum_{c'<c} partial16[c'][b]
__global__ void k_base(const unsigned short* __restrict__ partial16,
                       const int* __restrict__ rp, int* __restrict__ base) {
  int b = blockIdx.x * blockDim.x + threadIdx.x;
  if (b >= NN) return;
  int run = rp[b];
#pragma unroll
  for (int c = 0; c < HC; ++c) {
    base[(size_t)c * NN + b] = run;
    run += (int)partial16[(size_t)c * NN + b];
  }
}

// graph boundaries from sorted batch
__global__ void k_bounds(const int* __restrict__ batch, int* __restrict__ starts) {
  int i = blockIdx.x * blockDim.x + threadIdx.x;
  if (i > NN) return;
  if (i == 0) {
    int b0 = batch[0];
    for (int g = 0; g <= b0; ++g) starts[g] = 0;
  } else if (i == NN) {
    int bl = batch[NN - 1];
    for (int g = bl + 1; g <= NG; ++g) starts[g] = NN;
  } else {
    int a = batch[i - 1], b = batch[i];
    for (int g = a + 1; g <= b; ++g) starts[g] = i;
  }
}

// in-CSR fill (keyed by dst): csr_pk = ((dst&127)<<16)|src, csr_norm
__global__ __launch_bounds__(256) void k_fill2(const int* __restrict__ src,
                                               const int* __restrict__ dst,
                                               const int* __restrict__ base,
                                               const float* __restrict__ dinv,
                                               unsigned int* __restrict__ csr_pk,
                                               float* __restrict__ csr_norm) {
  __shared__ unsigned int pos[FBINS];  // 64 KB
  int tid = threadIdx.x;
  int c = blockIdx.x, p = blockIdx.y;
  int b0 = p * FBINS;
  for (int w = tid; w < FBINS; w += 256) {
    int gb = b0 + w;
    pos[w] = (gb < NN) ? (unsigned int)base[(size_t)c * NN + gb] : 0u;
  }
  __syncthreads();
  int lo = c * EPC, hi = lo + EPC;
  for (int i = lo + tid; i < hi; i += 256) {
    int d = dst[i];
    int s = src[i];
    int rel = d - b0;
    if ((unsigned)rel < (unsigned)FBINS) {
      int idx = (int)atomicAdd(&pos[rel], 1u);
      csr_pk[idx] = ((unsigned int)(d & (TN - 1)) << 16) | (unsigned int)s;
      csr_norm[idx] = dinv[s] * dinv[d];
    }
  }
}

// ---------------- conv1 aggregate: z = elu(A_norm @ h1 + b1), slice-major out ----------------
// grid (8 slices, NT dst-tiles): linear id % 8 = slice -> XCD L2 affinity (3.2 MB h1
// slice L2-resident). 8 groups x 32 lanes; meta loaded coalesced + shfl-broadcast;
// 8 independent gathers in flight; register accumulate, LDS ds_add only on dst-change.
__global__ __launch_bounds__(256) void k_agg1r(const unsigned short* __restrict__ h1,
                                               const unsigned int* __restrict__ csr_pk,
                                               const float* __restrict__ csr_nrm,
                                               const int* __restrict__ rp,
                                               const float* __restrict__ dinv,
                                               const float* __restrict__ b1,
                                               unsigned short* __restrict__ z) {
  __shared__ float acc[TN * 32];  // 16 KB
  int s = blockIdx.x, tb = blockIdx.y;
  int tid = threadIdx.x, f = tid & 31, eg = tid >> 5;
  const unsigned short* h1s = h1 + (size_t)s * MPAD * 32;
  int lo = tb * TN, hi = min(lo + TN, NN), nv = hi - lo;
  int e0 = rp[lo], e1 = rp[hi];
  for (int w = tid; w < TN * 32; w += 256) acc[w] = 0.f;
  float bias = b1[s * 32 + f];
  __syncthreads();
  int per = (e1 - e0 + 7) >> 3;
  int gs = e0 + eg * per, ge = min(gs + per, e1);
  float racc = 0.f; int cur = -1;
  for (int base = gs; base < ge; base += 32) {
    int n = min(32, ge - base);
    unsigned int pk = 0u; float nm = 0.f;
    if (f < n) { pk = csr_pk[base + f]; nm = csr_nrm[base + f]; }
    for (int t0 = 0; t0 < n; t0 += 8) {
      unsigned int pkt[8]; float val[8];
#pragma unroll
      for (int t = 0; t < 8; ++t) {
        pkt[t] = (unsigned int)__shfl((int)pk, t0 + t, 32);
        float nmt = __shfl(nm, t0 + t, 32);
        val[t] = nmt * bf2f(h1s[(size_t)(pkt[t] & 0xffffu) * 32 + f]);
      }
#pragma unroll
      for (int t = 0; t < 8; ++t) {
        int rel = (int)(pkt[t] >> 16);
        if (rel != cur) {
          if (cur >= 0) atomicAdd(&acc[cur * 32 + f], racc);
          racc = 0.f; cur = rel;
        }
        racc += val[t];
      }
    }
  }
  if (cur >= 0) atomicAdd(&acc[cur * 32 + f], racc);
  __syncthreads();
  // epilogue: self-loop + bias + ELU + slice-major write
  for (int i = eg; i < nv; i += 8) {
    int v = lo + i;
    float di = dinv[v];
    float t = acc[i * 32 + f] + di * di * bf2f(h1s[(size_t)v * 32 + f]) + bias;
    float ez = t > 0.f ? t : expm1f(t);
    z[((size_t)s * NN + v) * 32 + f] = f2bf(ez);
  }
}

// ---------------- conv2+pool aggregate: part2[s][tb][g][f] from same dst-CSR ----------------
// identical skeleton; gathers slice-major z (same-XCD L2 hit); flush on GRAPH change
// (~1 per tile); self-loop epilogue; per-block [64][32] pool tile.
__global__ __launch_bounds__(256) void k_agg2r(const unsigned short* __restrict__ z,
                                               const unsigned int* __restrict__ csr_pk,
                                               const float* __restrict__ csr_nrm,
                                               const int* __restrict__ rp,
                                               const float* __restrict__ dinv,
                                               const int* __restrict__ batch,
                                               float* __restrict__ part2) {
  __shared__ float pool[NG * 32];  // 8 KB
  __shared__ int g8[TN];
  int s = blockIdx.x, tb = blockIdx.y;
  int tid = threadIdx.x, f = tid & 31, eg = tid >> 5;
  const unsigned short* zs = z + (size_t)s * NN * 32;
  int lo = tb * TN, hi = min(lo + TN, NN), nv = hi - lo;
  int e0 = rp[lo], e1 = rp[hi];
  for (int w = tid; w < NG * 32; w += 256) pool[w] = 0.f;
  for (int w = tid; w < nv; w += 256) g8[w] = batch[lo + w];
  __syncthreads();
  int per = (e1 - e0 + 7) >> 3;
  int gs = e0 + eg * per, ge = min(gs + per, e1);
  float racc = 0.f; int cur = -1, curg = -1;
  for (int base = gs; base < ge; base += 32) {
    int n = min(32, ge - base);
    unsigned int pk = 0u; float nm = 0.f;
    if (f < n) { pk = csr_pk[base + f]; nm = csr_nrm[base + f]; }
    for (int t0 = 0; t0 < n; t0 += 8) {
      unsigned int pkt[8]; float val[8];
#pragma unroll
      for (int t = 0; t < 8; ++t) {
        pkt[t] = (unsigned int)__shfl((int)pk, t0 + t, 32);
        float nmt = __shfl(nm, t0 + t, 32);
        val[t] = nmt * bf2f(zs[(size_t)(pkt[t] & 0xffffu) * 32 + f]);
      }
#pragma unroll
      for (int t = 0; t < 8; ++t) {
        int rel = (int)(pkt[t] >> 16);
        if (rel != cur) {
          cur = rel;
          int g = g8[rel];
          if (g != curg) {
            if (curg >= 0) atomicAdd(&pool[curg * 32 + f], racc);
            racc = 0.f; curg = g;
          }
        }
        racc += val[t];
      }
    }
  }
  if (curg >= 0) atomicAdd(&pool[curg * 32 + f], racc);
  __syncthreads();
  // self-loop terms
  for (int i = eg; i < nv; i += 8) {
    int v = lo + i;
    float di = dinv[v];
    atomicAdd(&pool[g8[i] * 32 + f], di * di * bf2f(zs[(size_t)v * 32 + f]));
  }
  __syncthreads();
  float* dst = part2 + (size_t)(s * NT + tb) * NG * 32;
  for (int w = tid; w < NG * 32; w += 256) dst[w] = pool[w];
}

// pool[g][s*32+f] = sum over tiles
__global__ __launch_bounds__(256) void k_pred2(const float* __restrict__ part2,
                                               float* __restrict__ pool) {
  int g = blockIdx.x, j = threadIdx.x;
  int s = j >> 5, f = j & 31;
  float acc = 0.f;
  for (int tb = 0; tb < NT; ++tb)
    acc += part2[(size_t)(s * NT + tb) * NG * 32 + g * 32 + f];
  pool[g * 256 + j] = acc;
}

// ---------------- f = (pool/c) @ W2 + b2 ----------------
__global__ __launch_bounds__(256) void k_featF(const float* __restrict__ pool_s,
                                               const float* __restrict__ pool_n,
                                               const int* __restrict__ st_s,
                                               const int* __restrict__ st_n,
                                               const float* __restrict__ W2,
                                               const float* __restrict__ b2,
                                               float* __restrict__ fstate,
                                               float* __restrict__ fnext,
                                               float* __restrict__ out) {
  int g = blockIdx.x, which = blockIdx.y, j = threadIdx.x;
  const float* pool = which ? pool_n : pool_s;
  const int* st = which ? st_n : st_s;
  int c = st[g + 1] - st[g];
  __shared__ float v[256];
  float cc = fmaxf((float)c, 1.0f);
  v[j] = pool[g * 256 + j] / cc;
  __syncthreads();
  float acc = 0.f;
  for (int k = 0; k < 256; ++k) acc += v[k] * W2[k * 256 + j];
  float val = (c > 0) ? (acc + b2[j]) : 0.f;
  if (which) { fnext[g * 256 + j] = val; out[g * 256 + j] = val; }
  else fstate[g * 256 + j] = val;
}

// ---------------- heads ----------------
__global__ __launch_bounds__(256) void k_head(const float* __restrict__ fstate,
                                              const float* __restrict__ fnext,
                                              const int* __restrict__ action,
                                              const float* __restrict__ Wf, const float* __restrict__ bfv,
                                              const float* __restrict__ Wi1, const float* __restrict__ bi1,
                                              const float* __restrict__ Wi2, const float* __restrict__ bi2,
                                              const float* __restrict__ Wi3, const float* __restrict__ bi3,
                                              float* __restrict__ out) {
  int g = blockIdx.x, j = threadIdx.x;
  __shared__ float fs[256], fn_[256], z1[128], z2[128];
  fs[j] = fstate[g * 256 + j];
  fn_[j] = fnext[g * 256 + j];
  __syncthreads();
  int a = action[g];
  float acc = bfv[j] + Wf[a * 256 + j];
  for (int k = 0; k < 256; ++k) acc += fs[k] * Wf[(16 + k) * 256 + j];
  out[16384 + g * 256 + j] = acc;
  if (j < 128) {
    float t = bi1[j];
    for (int k = 0; k < 256; ++k)
      t += fs[k] * Wi1[k * 128 + j] + fn_[k] * Wi1[(256 + k) * 128 + j];
    z1[j] = fmaxf(t, 0.f);
  }
  __syncthreads();
  if (j < 128) {
    float t = bi2[j];
    for (int k = 0; k < 128; ++k) t += z1[k] * Wi2[k * 128 + j];
    z2[j] = fmaxf(t, 0.f);
  }
  __syncthreads();
  if (j < 16) {
    float t = bi3[j];
    for (int k = 0; k < 128; ++k) t += z2[k] * Wi3[k * 16 + j];
    out[32768 + g * 16 + j] = t;
  }
}

// ---------------- workspace layout ----------------
static constexpr size_t AL(size_t x) { return (x + 255) & ~(size_t)255; }
static constexpr size_t O_XB   = 0;                                    // 25.6 MB (part2 aliases)
static constexpr size_t O_H1   = O_XB + AL((size_t)MPAD * DD * 2);     // 25.6 MB (sort scratch aliases)
static constexpr size_t O_Z    = O_H1 + AL((size_t)MPAD * DD * 2);     // 25.6 MB slice-major z
static constexpr size_t O_CSRS = O_Z + AL((size_t)NN * DD * 2);
static constexpr size_t O_CSRN = O_CSRS + AL((size_t)NE * 4);
static constexpr size_t O_RP   = O_CSRN + AL((size_t)NE * 4);
static constexpr size_t O_DINV = O_RP + AL((size_t)(NN + 1) * 4);
static constexpr size_t O_DEG  = O_DINV + AL((size_t)NN * 4);
static constexpr size_t O_BS   = O_DEG + AL((size_t)NN * 4);
static constexpr size_t O_ST0  = O_BS + AL(256 * 4);
static constexpr size_t O_ST1  = O_ST0 + AL((NG + 1) * 4);
static constexpr size_t O_WT   = O_ST1 + AL((NG + 1) * 4);
static constexpr size_t O_PS   = O_WT + AL((size_t)DD * DD * 2);
static constexpr size_t O_PN   = O_PS + AL((size_t)NG * DD * 4);
static constexpr size_t O_FS   = O_PN + AL((size_t)NG * DD * 4);
static constexpr size_t O_FN   = O_FS + AL((size_t)NG * DD * 4);
static constexpr size_t O_END  = O_FN + AL((size_t)NG * DD * 4);
// aliased scratch:
static constexpr size_t O_PART = O_H1;                                  // HC*NN/2 u32 = 6.4 MB
static constexpr size_t O_BASE = O_H1 + AL((size_t)HC * (NN / 2) * 4);  // HC*NN u32 = 12.8 MB
static constexpr size_t O_PB   = O_XB;                                  // 8*NT*64*32*4 = 25.6 MB

extern "C" void kernel_launch(void* const* d_in, const int* in_sizes, int n_in,
                              void* d_out, int out_size, void* d_ws, size_t ws_size,
                              hipStream_t stream) {
  const float* x_s     = (const float*)d_in[0];
  const int*   ei_s    = (const int*)d_in[1];
  const int*   batch_s = (const int*)d_in[2];
  const float* x_n     = (const float*)d_in[3];
  const int*   ei_n    = (const int*)d_in[4];
  const int*   batch_n = (const int*)d_in[5];
  const int*   action  = (const int*)d_in[6];
  const float* W1      = (const float*)d_in[7];
  const float* b1      = (const float*)d_in[8];
  const float* W2      = (const float*)d_in[9];
  const float* b2      = (const float*)d_in[10];
  const float* Wf      = (const float*)d_in[11];
  const float* bfv     = (const float*)d_in[12];
  const float* Wi1     = (const float*)d_in[13];
  const float* bi1     = (const float*)d_in[14];
  const float* Wi2     = (const float*)d_in[15];
  const float* bi2     = (const float*)d_in[16];
  const float* Wi3     = (const float*)d_in[17];
  const float* bi3     = (const float*)d_in[18];
  float* out = (float*)d_out;
  char* ws = (char*)d_ws;
  if (ws_size < O_END) return;

  unsigned short* xb  = (unsigned short*)(ws + O_XB);
  unsigned short* h1  = (unsigned short*)(ws + O_H1);
  unsigned short* zb  = (unsigned short*)(ws + O_Z);
  unsigned int* csr_pk = (unsigned int*)(ws + O_CSRS);
  float* csr_nrm = (float*)(ws + O_CSRN);
  int*   rp      = (int*)(ws + O_RP);
  float* dinv    = (float*)(ws + O_DINV);
  int*   deg     = (int*)(ws + O_DEG);
  int*   bsums   = (int*)(ws + O_BS);
  unsigned short* Wt = (unsigned short*)(ws + O_WT);
  float* fstate  = (float*)(ws + O_FS);
  float* fnext   = (float*)(ws + O_FN);
  int*   starts[2] = { (int*)(ws + O_ST0), (int*)(ws + O_ST1) };
  float* pool[2]   = { (float*)(ws + O_PS), (float*)(ws + O_PN) };
  unsigned int* partial = (unsigned int*)(ws + O_PART);
  int*          basebuf = (int*)(ws + O_BASE);
  float*        part2   = (float*)(ws + O_PB);

  k_castW<<<(DD * DD) / 256, 256, 0, stream>>>(W1, Wt);

  const float* xs[2]  = { x_s, x_n };
  const int*   eis[2] = { ei_s, ei_n };
  const int*   bts[2] = { batch_s, batch_n };

  for (int gidx = 0; gidx < 2; ++gidx) {
    const float* x = xs[gidx];
    const int* src = eis[gidx];
    const int* dst = eis[gidx] + NE;
    const int* batch = bts[gidx];

    k_castX<<<(MPAD * DD / 4) / 256, 256, 0, stream>>>(x, xb);

    // --- in-CSR (by dst): deg -> dinv, rp, csr_pk/csr_norm ---
    k_hist2<<<dim3(HC, 2), 256, 0, stream>>>(dst, partial);
    k_reduce<<<(NN / 2 + 255) / 256, 256, 0, stream>>>(partial, deg);
    k_dinv<<<(NN + 255) / 256, 256, 0, stream>>>(deg, dinv);
    k_bsum<<<SB, 256, 0, stream>>>(deg, bsums);
    k_sscan<<<1, 256, 0, stream>>>(bsums);
    k_fillrp<<<SB, 256, 0, stream>>>(deg, bsums, rp);
    k_base<<<(NN + 255) / 256, 256, 0, stream>>>((const unsigned short*)partial, rp, basebuf);
    k_fill2<<<dim3(HC, (NN + FBINS - 1) / FBINS), 256, 0, stream>>>(src, dst, basebuf, dinv,
                                                                    csr_pk, csr_nrm);
    k_bounds<<<(NN + 1 + 255) / 256, 256, 0, stream>>>(batch, starts[gidx]);

    // --- dense GEMM (frees sort scratch), then the two sliced aggregations ---
    k_gemm<<<dim3(MPAD / 128, DD / 64), 256, 0, stream>>>(xb, Wt, h1);
    k_agg1r<<<dim3(8, NT), 256, 0, stream>>>(h1, csr_pk, csr_nrm, rp, dinv, b1, zb);
    k_agg2r<<<dim3(8, NT), 256, 0, stream>>>(zb, csr_pk, csr_nrm, rp, dinv, batch, part2);
    k_pred2<<<NG, 256, 0, stream>>>(part2, pool[gidx]);
  }

  k_featF<<<dim3(NG, 2), 256, 0, stream>>>(pool[0], pool[1], starts[0], starts[1], W2, b2,
                                           fstate, fnext, out);
  k_head<<<NG, 256, 0, stream>>>(fstate, fnext, action, Wf, bfv,
                                 Wi1, bi1, Wi2, bi2, Wi3, bi3, out);
}

// Round 8
// 859.441 us; speedup vs baseline: 3.4278x; 1.1559x over previous
//
#include <hip/hip_runtime.h>

#define NN 50000
#define NE 800000
#define DD 256
#define NG 64
#define MPAD 50048  // 128 * 391

// counting-sort parameters
#define HC 64          // edge chunks (NE/HC = 12500)
#define EPC (NE / HC)  // 12500
#define HBINS 32768    // bins/part, u16-packed -> 64 KB LDS (2 parts)
#define FBINS 16384    // bins/part, u32 counters -> 64 KB LDS (4 parts)

// parallel scan
#define SB 196         // SB*256 = 50176 >= NN+1

// tiled aggregation
#define TN 128                    // dst nodes per tile (128-aligned -> rel = dst & 127)
#define NT ((NN + TN - 1) / TN)   // 391

typedef __attribute__((ext_vector_type(8))) short bf16x8;
typedef __attribute__((ext_vector_type(4))) float f32x4;

__device__ __forceinline__ float bf2f(unsigned short u) {
  union { unsigned int i; float f; } v; v.i = ((unsigned int)u) << 16; return v.f;
}
__device__ __forceinline__ unsigned short f2bf(float f) {
  union { float f; unsigned int i; } v; v.f = f;
  unsigned int x = v.i;
  x += 0x7fffu + ((x >> 16) & 1u);  // RNE
  return (unsigned short)(x >> 16);
}

// ---------------- casts ----------------
__global__ void k_castW(const float* __restrict__ W, unsigned short* __restrict__ Wt) {
  int i = blockIdx.x * blockDim.x + threadIdx.x;
  int n = i >> 8, k = i & 255;
  Wt[i] = f2bf(W[k * 256 + n]);
}

__global__ void k_castX(const float* __restrict__ x, unsigned short* __restrict__ xb) {
  int i = blockIdx.x * blockDim.x + threadIdx.x;
  int e = i * 4;
  int row = e >> 8;
  float4 v = make_float4(0.f, 0.f, 0.f, 0.f);
  if (row < NN) v = *(const float4*)(x + e);
  ushort4 u;
  u.x = f2bf(v.x); u.y = f2bf(v.y); u.z = f2bf(v.z); u.w = f2bf(v.w);
  *(ushort4*)(xb + e) = u;
}

// ---------------- GEMM: h1' (slice-major [8][MPAD][32]) = dinv .* (A @ B) ----------------
__global__ __launch_bounds__(256) void k_gemm(const unsigned short* __restrict__ A,
                                              const unsigned short* __restrict__ Bt,
                                              const float* __restrict__ dinv,
                                              unsigned short* __restrict__ C) {
  __shared__ unsigned short As[128][40];
  __shared__ unsigned short Bs[64][40];
  int tid = threadIdx.x;
  int lane = tid & 63;
  int wave = tid >> 6;
  int wm = wave >> 1, wn = wave & 1;
  int m0 = blockIdx.x * 128, n0 = blockIdx.y * 64;
  int l15 = lane & 15, l4 = lane >> 4;
  f32x4 acc[4][2] = {};

  for (int ks = 0; ks < 8; ++ks) {
    int k0 = ks * 32;
    {
      int c = tid, r = c >> 2, cc = c & 3;
      *(uint4*)(&As[r][cc * 8]) = *(const uint4*)(A + (size_t)(m0 + r) * 256 + k0 + cc * 8);
      c = tid + 256; r = c >> 2; cc = c & 3;
      *(uint4*)(&As[r][cc * 8]) = *(const uint4*)(A + (size_t)(m0 + r) * 256 + k0 + cc * 8);
      c = tid; r = c >> 2; cc = c & 3;
      *(uint4*)(&Bs[r][cc * 8]) = *(const uint4*)(Bt + (size_t)(n0 + r) * 256 + k0 + cc * 8);
    }
    __syncthreads();
    bf16x8 a[4], b[2];
#pragma unroll
    for (int fm = 0; fm < 4; ++fm)
      a[fm] = *(const bf16x8*)(&As[wm * 64 + fm * 16 + l15][l4 * 8]);
#pragma unroll
    for (int fn = 0; fn < 2; ++fn)
      b[fn] = *(const bf16x8*)(&Bs[wn * 32 + fn * 16 + l15][l4 * 8]);
#pragma unroll
    for (int fm = 0; fm < 4; ++fm)
#pragma unroll
      for (int fn = 0; fn < 2; ++fn)
        acc[fm][fn] = __builtin_amdgcn_mfma_f32_16x16x32_bf16(a[fm], b[fn], acc[fm][fn], 0, 0, 0);
    __syncthreads();
  }
  int r0 = l4 * 4;
#pragma unroll
  for (int fm = 0; fm < 4; ++fm)
#pragma unroll
    for (int fn = 0; fn < 2; ++fn) {
      int row = m0 + wm * 64 + fm * 16 + r0;
      int col = n0 + wn * 32 + fn * 16 + l15;
      size_t sbase = (size_t)(col >> 5) * MPAD * 32 + (size_t)(col & 31);
#pragma unroll
      for (int r = 0; r < 4; ++r) {
        int rr = row + r;
        float dv = dinv[rr < NN ? rr : 0];
        C[sbase + (size_t)rr * 32] = f2bf(dv * acc[fm][fn][r]);
      }
    }
}

// ---------------- counting sort (by dst) ----------------
__global__ __launch_bounds__(256) void k_hist2(const int* __restrict__ key,
                                               unsigned int* __restrict__ partial) {
  __shared__ unsigned int lh[HBINS / 2];  // 64 KB u16-packed
  int tid = threadIdx.x;
  int c = blockIdx.x, p = blockIdx.y;
  for (int w = tid; w < HBINS / 2; w += 256) lh[w] = 0u;
  __syncthreads();
  int lo = c * EPC, hi = lo + EPC;
  int b0 = p * HBINS;
  for (int i = lo + tid; i < hi; i += 256) {
    int rel = key[i] - b0;
    if ((unsigned)rel < (unsigned)HBINS)
      atomicAdd(&lh[rel >> 1], 1u << ((rel & 1) * 16));
  }
  __syncthreads();
  int wbase = p * (HBINS / 2);
  for (int w = tid; w < HBINS / 2; w += 256) {
    int gw = wbase + w;
    if (gw < NN / 2) partial[(size_t)c * (NN / 2) + gw] = lh[w];
  }
}

__global__ void k_reduce(const unsigned int* __restrict__ partial, int* __restrict__ deg) {
  int w = blockIdx.x * blockDim.x + threadIdx.x;
  if (w >= NN / 2) return;
  unsigned int sl = 0, sh = 0;
#pragma unroll
  for (int c = 0; c < HC; ++c) {
    unsigned int v = partial[(size_t)c * (NN / 2) + w];
    sl += v & 0xffffu;
    sh += v >> 16;
  }
  *(int2*)(deg + 2 * w) = make_int2((int)sl, (int)sh);
}

__global__ void k_dinv(const int* __restrict__ deg, float* __restrict__ dinv) {
  int i = blockIdx.x * blockDim.x + threadIdx.x;
  if (i < NN) dinv[i] = rsqrtf((float)deg[i] + 1.0f);  // +1 self-loop
}

// 3-dispatch parallel exclusive scan: deg[NN] -> rp[NN+1]
__global__ __launch_bounds__(256) void k_bsum(const int* __restrict__ deg, int* __restrict__ bsums) {
  __shared__ int s[256];
  int b = blockIdx.x, t = threadIdx.x, i = b * 256 + t;
  int v = (i < NN) ? deg[i] : 0;
  s[t] = v; __syncthreads();
  for (int off = 128; off > 0; off >>= 1) {
    if (t < off) s[t] += s[t + off];
    __syncthreads();
  }
  if (t == 0) bsums[b] = s[0];
}
__global__ __launch_bounds__(256) void k_sscan(int* __restrict__ bsums) {
  __shared__ int s[256];
  int t = threadIdx.x;
  int v = (t < SB) ? bsums[t] : 0;
  s[t] = v; __syncthreads();
  for (int off = 1; off < 256; off <<= 1) {
    int tmp = (t >= off) ? s[t - off] : 0;
    __syncthreads();
    s[t] += tmp;
    __syncthreads();
  }
  if (t < SB) bsums[t] = s[t] - v;  // exclusive
}
__global__ __launch_bounds__(256) void k_fillrp(const int* __restrict__ deg,
                                                const int* __restrict__ bsums,
                                                int* __restrict__ rp) {
  __shared__ int s[256];
  int b = blockIdx.x, t = threadIdx.x, i = b * 256 + t;
  int v = (i < NN) ? deg[i] : 0;
  s[t] = v; __syncthreads();
  for (int off = 1; off < 256; off <<= 1) {
    int tmp = (t >= off) ? s[t - off] : 0;
    __syncthreads();
    s[t] += tmp;
    __syncthreads();
  }
  int excl = bsums[b] + s[t] - v;
  if (i <= NN) rp[i] = excl;
}

// base[c][b] = rp[b] + sum_{c'<c} partial16[c'][b]
__global__ void k_base(const unsigned short* __restrict__ partial16,
                       const int* __restrict__ rp, int* __restrict__ base) {
  int b = blockIdx.x * blockDim.x + threadIdx.x;
  if (b >= NN) return;
  int run = rp[b];
#pragma unroll
  for (int c = 0; c < HC; ++c) {
    base[(size_t)c * NN + b] = run;
    run += (int)partial16[(size_t)c * NN + b];
  }
}

// graph boundaries from sorted batch
__global__ void k_bounds(const int* __restrict__ batch, int* __restrict__ starts) {
  int i = blockIdx.x * blockDim.x + threadIdx.x;
  if (i > NN) return;
  if (i == 0) {
    int b0 = batch[0];
    for (int g = 0; g <= b0; ++g) starts[g] = 0;
  } else if (i == NN) {
    int bl = batch[NN - 1];
    for (int g = bl + 1; g <= NG; ++g) starts[g] = NN;
  } else {
    int a = batch[i - 1], b = batch[i];
    for (int g = a + 1; g <= b; ++g) starts[g] = i;
  }
}

// in-CSR fill (keyed by dst): csr_pk = ((dst&127)<<16)|src  (no norm needed anymore)
__global__ __launch_bounds__(256) void k_fill2(const int* __restrict__ src,
                                               const int* __restrict__ dst,
                                               const int* __restrict__ base,
                                               unsigned int* __restrict__ csr_pk) {
  __shared__ unsigned int pos[FBINS];  // 64 KB
  int tid = threadIdx.x;
  int c = blockIdx.x, p = blockIdx.y;
  int b0 = p * FBINS;
  for (int w = tid; w < FBINS; w += 256) {
    int gb = b0 + w;
    pos[w] = (gb < NN) ? (unsigned int)base[(size_t)c * NN + gb] : 0u;
  }
  __syncthreads();
  int lo = c * EPC, hi = lo + EPC;
  for (int i = lo + tid; i < hi; i += 256) {
    int d = dst[i];
    int s = src[i];
    int rel = d - b0;
    if ((unsigned)rel < (unsigned)FBINS) {
      int idx = (int)atomicAdd(&pos[rel], 1u);
      csr_pk[idx] = ((unsigned int)(d & (TN - 1)) << 16) | (unsigned int)s;
    }
  }
}

// ---------------- conv1 aggregate: z' = dinv * elu(dinv*(sum h1'[s] + h1'[d]) + b1) ----------
// grid (8 slices, NT dst-tiles): linear id % 8 = slice -> XCD L2 affinity.
// inner loop per edge: shfl(pk) -> gather h1' -> add. No norm. 16-deep gather batch.
__global__ __launch_bounds__(256) void k_agg1r(const unsigned short* __restrict__ h1,
                                               const unsigned int* __restrict__ csr_pk,
                                               const int* __restrict__ rp,
                                               const float* __restrict__ dinv,
                                               const float* __restrict__ b1,
                                               unsigned short* __restrict__ z) {
  __shared__ float acc[TN * 32];  // 16 KB
  int s = blockIdx.x, tb = blockIdx.y;
  int tid = threadIdx.x, f = tid & 31, eg = tid >> 5;
  const unsigned short* h1s = h1 + (size_t)s * MPAD * 32;
  int lo = tb * TN, hi = min(lo + TN, NN), nv = hi - lo;
  int e0 = rp[lo], e1 = rp[hi];
  for (int w = tid; w < TN * 32; w += 256) acc[w] = 0.f;
  float bias = b1[s * 32 + f];
  __syncthreads();
  int per = (e1 - e0 + 7) >> 3;
  int gs = e0 + eg * per, ge = min(gs + per, e1);
  float racc = 0.f; int cur = -1;
  unsigned int cpk = 0u;
  if (gs + f < ge) cpk = csr_pk[gs + f];
  for (int bb = gs; bb < ge; bb += 32) {
    int n = min(32, ge - bb);
    unsigned int npk = 0u;
    if (bb + 32 + f < ge) npk = csr_pk[bb + 32 + f];
    for (int t0 = 0; t0 < n; t0 += 16) {
      int m = n - t0; m = m > 16 ? 16 : m;
      if (m == 16) {
        unsigned int pkt[16]; float val[16];
#pragma unroll
        for (int t = 0; t < 16; ++t)
          pkt[t] = (unsigned int)__shfl((int)cpk, t0 + t, 32);
#pragma unroll
        for (int t = 0; t < 16; ++t)
          val[t] = bf2f(h1s[(size_t)(pkt[t] & 0xffffu) * 32 + f]);
#pragma unroll
        for (int t = 0; t < 16; ++t) {
          int rel = (int)(pkt[t] >> 16);
          if (rel != cur) {
            if (cur >= 0) atomicAdd(&acc[cur * 32 + f], racc);
            racc = 0.f; cur = rel;
          }
          racc += val[t];
        }
      } else {
        for (int t = 0; t < m; ++t) {
          unsigned int pk = (unsigned int)__shfl((int)cpk, t0 + t, 32);
          float v = bf2f(h1s[(size_t)(pk & 0xffffu) * 32 + f]);
          int rel = (int)(pk >> 16);
          if (rel != cur) {
            if (cur >= 0) atomicAdd(&acc[cur * 32 + f], racc);
            racc = 0.f; cur = rel;
          }
          racc += v;
        }
      }
    }
    cpk = npk;
  }
  if (cur >= 0) atomicAdd(&acc[cur * 32 + f], racc);
  __syncthreads();
  // epilogue: t = dinv*(acc + h1'[v]) + b1 ; z' = dinv*elu(t)
  for (int i = eg; i < nv; i += 8) {
    int v = lo + i;
    float di = dinv[v];
    float t = di * (acc[i * 32 + f] + bf2f(h1s[(size_t)v * 32 + f])) + bias;
    float ez = t > 0.f ? t : expm1f(t);
    z[((size_t)s * NN + v) * 32 + f] = f2bf(di * ez);
  }
}

// ---------------- conv2+pool aggregate from same dst-CSR, gathering z' ----------------
// per-dst sum of z'[s]; on dst-change multiply by s_di[dst] into per-graph reg acc;
// flush to LDS pool tile on graph-change.
__global__ __launch_bounds__(256) void k_agg2r(const unsigned short* __restrict__ z,
                                               const unsigned int* __restrict__ csr_pk,
                                               const int* __restrict__ rp,
                                               const float* __restrict__ dinv,
                                               const int* __restrict__ batch,
                                               float* __restrict__ part2) {
  __shared__ float pool[NG * 32];  // 8 KB
  __shared__ int g8[TN];
  __shared__ float s_di[TN];
  int s = blockIdx.x, tb = blockIdx.y;
  int tid = threadIdx.x, f = tid & 31, eg = tid >> 5;
  const unsigned short* zs = z + (size_t)s * NN * 32;
  int lo = tb * TN, hi = min(lo + TN, NN), nv = hi - lo;
  int e0 = rp[lo], e1 = rp[hi];
  for (int w = tid; w < NG * 32; w += 256) pool[w] = 0.f;
  for (int w = tid; w < nv; w += 256) { g8[w] = batch[lo + w]; s_di[w] = dinv[lo + w]; }
  __syncthreads();
  int per = (e1 - e0 + 7) >> 3;
  int gs = e0 + eg * per, ge = min(gs + per, e1);
  float rd = 0.f, rg = 0.f; int cur = -1, curg = -1;
  unsigned int cpk = 0u;
  if (gs + f < ge) cpk = csr_pk[gs + f];
  for (int bb = gs; bb < ge; bb += 32) {
    int n = min(32, ge - bb);
    unsigned int npk = 0u;
    if (bb + 32 + f < ge) npk = csr_pk[bb + 32 + f];
    for (int t0 = 0; t0 < n; t0 += 16) {
      int m = n - t0; m = m > 16 ? 16 : m;
      if (m == 16) {
        unsigned int pkt[16]; float val[16];
#pragma unroll
        for (int t = 0; t < 16; ++t)
          pkt[t] = (unsigned int)__shfl((int)cpk, t0 + t, 32);
#pragma unroll
        for (int t = 0; t < 16; ++t)
          val[t] = bf2f(zs[(size_t)(pkt[t] & 0xffffu) * 32 + f]);
#pragma unroll
        for (int t = 0; t < 16; ++t) {
          int rel = (int)(pkt[t] >> 16);
          if (rel != cur) {
            if (cur >= 0) rg += s_di[cur] * rd;
            rd = 0.f;
            int g = g8[rel];
            if (g != curg) {
              if (curg >= 0) atomicAdd(&pool[curg * 32 + f], rg);
              rg = 0.f; curg = g;
            }
            cur = rel;
          }
          rd += val[t];
        }
      } else {
        for (int t = 0; t < m; ++t) {
          unsigned int pk = (unsigned int)__shfl((int)cpk, t0 + t, 32);
          float v = bf2f(zs[(size_t)(pk & 0xffffu) * 32 + f]);
          int rel = (int)(pk >> 16);
          if (rel != cur) {
            if (cur >= 0) rg += s_di[cur] * rd;
            rd = 0.f;
            int g = g8[rel];
            if (g != curg) {
              if (curg >= 0) atomicAdd(&pool[curg * 32 + f], rg);
              rg = 0.f; curg = g;
            }
            cur = rel;
          }
          rd += v;
        }
      }
    }
    cpk = npk;
  }
  if (cur >= 0) rg += s_di[cur] * rd;
  if (curg >= 0) atomicAdd(&pool[curg * 32 + f], rg);
  __syncthreads();
  // self-loop terms: dinv[v]^2 * z[v] = s_di * z'
  for (int i = eg; i < nv; i += 8) {
    int v = lo + i;
    atomicAdd(&pool[g8[i] * 32 + f], s_di[i] * bf2f(zs[(size_t)v * 32 + f]));
  }
  __syncthreads();
  float* dst = part2 + (size_t)(s * NT + tb) * NG * 32;
  for (int w = tid; w < NG * 32; w += 256) dst[w] = pool[w];
}

// pool[g][s*32+f] = sum over tiles
__global__ __launch_bounds__(256) void k_pred2(const float* __restrict__ part2,
                                               float* __restrict__ pool) {
  int g = blockIdx.x, j = threadIdx.x;
  int s = j >> 5, f = j & 31;
  float acc = 0.f;
  for (int tb = 0; tb < NT; ++tb)
    acc += part2[(size_t)(s * NT + tb) * NG * 32 + g * 32 + f];
  pool[g * 256 + j] = acc;
}

// ---------------- f = (pool/c) @ W2 + b2 ----------------
__global__ __launch_bounds__(256) void k_featF(const float* __restrict__ pool_s,
                                               const float* __restrict__ pool_n,
                                               const int* __restrict__ st_s,
                                               const int* __restrict__ st_n,
                                               const float* __restrict__ W2,
                                               const float* __restrict__ b2,
                                               float* __restrict__ fstate,
                                               float* __restrict__ fnext,
                                               float* __restrict__ out) {
  int g = blockIdx.x, which = blockIdx.y, j = threadIdx.x;
  const float* pool = which ? pool_n : pool_s;
  const int* st = which ? st_n : st_s;
  int c = st[g + 1] - st[g];
  __shared__ float v[256];
  float cc = fmaxf((float)c, 1.0f);
  v[j] = pool[g * 256 + j] / cc;
  __syncthreads();
  float acc = 0.f;
  for (int k = 0; k < 256; ++k) acc += v[k] * W2[k * 256 + j];
  float val = (c > 0) ? (acc + b2[j]) : 0.f;
  if (which) { fnext[g * 256 + j] = val; out[g * 256 + j] = val; }
  else fstate[g * 256 + j] = val;
}

// ---------------- heads ----------------
__global__ __launch_bounds__(256) void k_head(const float* __restrict__ fstate,
                                              const float* __restrict__ fnext,
                                              const int* __restrict__ action,
                                              const float* __restrict__ Wf, const float* __restrict__ bfv,
                                              const float* __restrict__ Wi1, const float* __restrict__ bi1,
                                              const float* __restrict__ Wi2, const float* __restrict__ bi2,
                                              const float* __restrict__ Wi3, const float* __restrict__ bi3,
                                              float* __restrict__ out) {
  int g = blockIdx.x, j = threadIdx.x;
  __shared__ float fs[256], fn_[256], z1[128], z2[128];
  fs[j] = fstate[g * 256 + j];
  fn_[j] = fnext[g * 256 + j];
  __syncthreads();
  int a = action[g];
  float acc = bfv[j] + Wf[a * 256 + j];
  for (int k = 0; k < 256; ++k) acc += fs[k] * Wf[(16 + k) * 256 + j];
  out[16384 + g * 256 + j] = acc;
  if (j < 128) {
    float t = bi1[j];
    for (int k = 0; k < 256; ++k)
      t += fs[k] * Wi1[k * 128 + j] + fn_[k] * Wi1[(256 + k) * 128 + j];
    z1[j] = fmaxf(t, 0.f);
  }
  __syncthreads();
  if (j < 128) {
    float t = bi2[j];
    for (int k = 0; k < 128; ++k) t += z1[k] * Wi2[k * 128 + j];
    z2[j] = fmaxf(t, 0.f);
  }
  __syncthreads();
  if (j < 16) {
    float t = bi3[j];
    for (int k = 0; k < 128; ++k) t += z2[k] * Wi3[k * 16 + j];
    out[32768 + g * 16 + j] = t;
  }
}

// ---------------- workspace layout ----------------
static constexpr size_t AL(size_t x) { return (x + 255) & ~(size_t)255; }
static constexpr size_t O_XB   = 0;                                    // 25.6 MB (part2 aliases)
static constexpr size_t O_H1   = O_XB + AL((size_t)MPAD * DD * 2);     // 25.6 MB (sort scratch aliases)
static constexpr size_t O_Z    = O_H1 + AL((size_t)MPAD * DD * 2);     // 25.6 MB slice-major z'
static constexpr size_t O_CSRS = O_Z + AL((size_t)NN * DD * 2);
static constexpr size_t O_RP   = O_CSRS + AL((size_t)NE * 4);
static constexpr size_t O_DINV = O_RP + AL((size_t)(NN + 1) * 4);
static constexpr size_t O_DEG  = O_DINV + AL((size_t)NN * 4);
static constexpr size_t O_BS   = O_DEG + AL((size_t)NN * 4);
static constexpr size_t O_ST0  = O_BS + AL(256 * 4);
static constexpr size_t O_ST1  = O_ST0 + AL((NG + 1) * 4);
static constexpr size_t O_WT   = O_ST1 + AL((NG + 1) * 4);
static constexpr size_t O_PS   = O_WT + AL((size_t)DD * DD * 2);
static constexpr size_t O_PN   = O_PS + AL((size_t)NG * DD * 4);
static constexpr size_t O_FS   = O_PN + AL((size_t)NG * DD * 4);
static constexpr size_t O_FN   = O_FS + AL((size_t)NG * DD * 4);
static constexpr size_t O_END  = O_FN + AL((size_t)NG * DD * 4);
// aliased scratch:
static constexpr size_t O_PART = O_H1;                                  // HC*NN/2 u32 = 6.4 MB
static constexpr size_t O_BASE = O_H1 + AL((size_t)HC * (NN / 2) * 4);  // HC*NN u32 = 12.8 MB
static constexpr size_t O_PB   = O_XB;                                  // 8*NT*64*32*4 = 25.6 MB

extern "C" void kernel_launch(void* const* d_in, const int* in_sizes, int n_in,
                              void* d_out, int out_size, void* d_ws, size_t ws_size,
                              hipStream_t stream) {
  const float* x_s     = (const float*)d_in[0];
  const int*   ei_s    = (const int*)d_in[1];
  const int*   batch_s = (const int*)d_in[2];
  const float* x_n     = (const float*)d_in[3];
  const int*   ei_n    = (const int*)d_in[4];
  const int*   batch_n = (const int*)d_in[5];
  const int*   action  = (const int*)d_in[6];
  const float* W1      = (const float*)d_in[7];
  const float* b1      = (const float*)d_in[8];
  const float* W2      = (const float*)d_in[9];
  const float* b2      = (const float*)d_in[10];
  const float* Wf      = (const float*)d_in[11];
  const float* bfv     = (const float*)d_in[12];
  const float* Wi1     = (const float*)d_in[13];
  const float* bi1     = (const float*)d_in[14];
  const float* Wi2     = (const float*)d_in[15];
  const float* bi2     = (const float*)d_in[16];
  const float* Wi3     = (const float*)d_in[17];
  const float* bi3     = (const float*)d_in[18];
  float* out = (float*)d_out;
  char* ws = (char*)d_ws;
  if (ws_size < O_END) return;

  unsigned short* xb  = (unsigned short*)(ws + O_XB);
  unsigned short* h1  = (unsigned short*)(ws + O_H1);
  unsigned short* zb  = (unsigned short*)(ws + O_Z);
  unsigned int* csr_pk = (unsigned int*)(ws + O_CSRS);
  int*   rp      = (int*)(ws + O_RP);
  float* dinv    = (float*)(ws + O_DINV);
  int*   deg     = (int*)(ws + O_DEG);
  int*   bsums   = (int*)(ws + O_BS);
  unsigned short* Wt = (unsigned short*)(ws + O_WT);
  float* fstate  = (float*)(ws + O_FS);
  float* fnext   = (float*)(ws + O_FN);
  int*   starts[2] = { (int*)(ws + O_ST0), (int*)(ws + O_ST1) };
  float* pool[2]   = { (float*)(ws + O_PS), (float*)(ws + O_PN) };
  unsigned int* partial = (unsigned int*)(ws + O_PART);
  int*          basebuf = (int*)(ws + O_BASE);
  float*        part2   = (float*)(ws + O_PB);

  k_castW<<<(DD * DD) / 256, 256, 0, stream>>>(W1, Wt);

  const float* xs[2]  = { x_s, x_n };
  const int*   eis[2] = { ei_s, ei_n };
  const int*   bts[2] = { batch_s, batch_n };

  for (int gidx = 0; gidx < 2; ++gidx) {
    const float* x = xs[gidx];
    const int* src = eis[gidx];
    const int* dst = eis[gidx] + NE;
    const int* batch = bts[gidx];

    k_castX<<<(MPAD * DD / 4) / 256, 256, 0, stream>>>(x, xb);

    // --- in-CSR (by dst): deg -> dinv, rp, csr_pk ---
    k_hist2<<<dim3(HC, 2), 256, 0, stream>>>(dst, partial);
    k_reduce<<<(NN / 2 + 255) / 256, 256, 0, stream>>>(partial, deg);
    k_dinv<<<(NN + 255) / 256, 256, 0, stream>>>(deg, dinv);
    k_bsum<<<SB, 256, 0, stream>>>(deg, bsums);
    k_sscan<<<1, 256, 0, stream>>>(bsums);
    k_fillrp<<<SB, 256, 0, stream>>>(deg, bsums, rp);
    k_base<<<(NN + 255) / 256, 256, 0, stream>>>((const unsigned short*)partial, rp, basebuf);
    k_fill2<<<dim3(HC, (NN + FBINS - 1) / FBINS), 256, 0, stream>>>(src, dst, basebuf, csr_pk);
    k_bounds<<<(NN + 1 + 255) / 256, 256, 0, stream>>>(batch, starts[gidx]);

    // --- dense GEMM with dinv pre-scale (frees sort scratch), then aggregations ---
    k_gemm<<<dim3(MPAD / 128, DD / 64), 256, 0, stream>>>(xb, Wt, dinv, h1);
    k_agg1r<<<dim3(8, NT), 256, 0, stream>>>(h1, csr_pk, rp, dinv, b1, zb);
    k_agg2r<<<dim3(8, NT), 256, 0, stream>>>(zb, csr_pk, rp, dinv, batch, part2);
    k_pred2<<<NG, 256, 0, stream>>>(part2, pool[gidx]);
  }

  k_featF<<<dim3(NG, 2), 256, 0, stream>>>(pool[0], pool[1], starts[0], starts[1], W2, b2,
                                           fstate, fnext, out);
  k_head<<<NG, 256, 0, stream>>>(fstate, fnext, action, Wf, bfv,
                                 Wi1, bi1, Wi2, bi2, Wi3, bi3, out);
}